// Round 12
// baseline (836.970 us; speedup 1.0000x reference)
//
#include <hip/hip_runtime.h>
#include <math.h>

typedef _Float16 half8  __attribute__((ext_vector_type(8)));
typedef _Float16 half4  __attribute__((ext_vector_type(4)));
typedef float    f32x16 __attribute__((ext_vector_type(16)));

#define T_DIM 36
#define N_AT 40
#define K_REAL 161
#define MT32 6          // 6 M-tiles of 32 = 192 rows (161 real; tile 5 = row 160 + pad)
#define KS16 11         // 11 K-steps of 16 = 176 (161 real, cols 161-175 zero)
#define KT 3            // DtY K-steps over t (36 -> 48)
#define B_DIM 2
#define F_DIM 20480
#define CB 32           // columns per block (one 32-wide MFMA N-tile)
#define NW 6
#define NTHREADS (NW * 64)   // 384; 6 waves, one M-tile each
#define SETUP_T 512     // frag builder needs tid>>3 to span 64 lanes
#define MAXIT 100
#define YKH 200         // y col stride in halves (400 B, 16B-aligned chunks)
#define YSTH 104        // staging col stride in halves (208 B)

// ws layout (bytes):
//  [0..64): scalars (float linv @0, float lam @4)
//  A-hat frags (32x32x16 A-operand): idx=(Mt*KS16+ks)*2+term, 64 lanes x 8 f16
//  Dthat frags: idx=(Mt*KT+ks2)*2+term
#define WS_AFRAG_OFF 64
#define AFRAG_BYTES (MT32 * KS16 * 2 * 1024)
#define WS_DFRAG_OFF (WS_AFRAG_OFF + AFRAG_BYTES)
#define DFRAG_BYTES (MT32 * KT * 2 * 1024)

#define MFMA32(a, b, c) __builtin_amdgcn_mfma_f32_32x32x16_f16((a), (b), (c), 0, 0, 0)

__global__ void setup_kernel(const float* __restrict__ Drr,
                             const float* __restrict__ Dtheta,
                             float* __restrict__ ws) {
    __shared__ float Dl[K_REAL][T_DIM];   // normalized dictionary, [col k][t]
    __shared__ float red[SETUP_T];
    __shared__ float s_linv;
    int tid = threadIdx.x;

    // ---- build normalized dictionary columns ----
    if (tid < K_REAL) {
        float col[T_DIM];
        if (tid == 0) {
            for (int i = 0; i < T_DIM; ++i) col[i] = 1.0f;
        } else {
            int q = (tid - 1) / N_AT, n = (tid - 1) % N_AT;
            float r = Drr[n], th = Dtheta[n];
            float ri = 1.0f;
            for (int i = 0; i < T_DIM; ++i) {
                float c = cosf((float)i * th), s = sinf((float)i * th);
                float sign = (i & 1) ? -1.0f : 1.0f;
                float v;
                if (q == 0)      v = ri * c;
                else if (q == 1) v = sign * ri * c;
                else if (q == 2) v = ri * s;
                else             v = sign * ri * s;
                col[i] = v;
                ri *= r;
            }
        }
        float ss = 0.0f;
        for (int i = 0; i < T_DIM; ++i) ss += col[i] * col[i];
        float G = sqrtf(ss);
        float Ginv = (G == 0.0f) ? (1.0f / sqrtf((float)T_DIM)) : (1.0f / G);
        for (int i = 0; i < T_DIM; ++i) Dl[tid][i] = col[i] * Ginv;
    }
    __syncthreads();

    // ---- linv = 1 / frobenius(DtD) ----
    float local = 0.0f;
    for (int p = tid; p < K_REAL * K_REAL; p += SETUP_T) {
        int a = p / K_REAL, b = p % K_REAL;
        float dot = 0.0f;
        for (int i = 0; i < T_DIM; ++i) dot += Dl[a][i] * Dl[b][i];
        local += dot * dot;
    }
    red[tid] = local;
    __syncthreads();
    if (tid == 0) {
        float tot = 0.0f;
        for (int i = 0; i < SETUP_T; ++i) tot += red[i];
        float linv = 1.0f / sqrtf(tot);
        s_linv = linv;
        ws[0] = linv;
        ws[1] = 0.1f * linv;
    }
    __syncthreads();
    float linv = s_linv;

    // ---- A-hat frags (32x32x16 A-operand): m = Mt*32+(lane&31),
    //      k = ks*16+(lane>>5)*8+e; zero outside the real 161x161 block ----
    _Float16* wsA = (_Float16*)((char*)ws + WS_AFRAG_OFF);
    int lane = tid >> 3, e = tid & 7;
    int fm = lane & 31, fg = lane >> 5;
    for (int p = 0; p < MT32 * KS16; ++p) {
        int Mt = p / KS16, ks = p % KS16;
        int m = Mt * 32 + fm;
        int k = ks * 16 + fg * 8 + e;
        float v = 0.0f;
        if (m < K_REAL && k < K_REAL) {
            float dot = 0.0f;
            for (int t = 0; t < T_DIM; ++t) dot += Dl[m][t] * Dl[k][t];
            v = ((m == k) ? 1.0f : 0.0f) - linv * dot;
        }
        _Float16 h = (_Float16)v;
        _Float16 l = (_Float16)(v - (float)h);
        int base = (p * 2) * 512 + lane * 8 + e;
        wsA[base]       = h;
        wsA[base + 512] = l;
    }

    // ---- Dthat frags: Dthat[k][t] = linv*D[t][k]; m-dim = k-row, K-dim = t ----
    _Float16* wsD = (_Float16*)((char*)ws + WS_DFRAG_OFF);
    for (int p = 0; p < MT32 * KT; ++p) {
        int Mt = p / KT, ks2 = p % KT;
        int kr = Mt * 32 + fm;
        int t  = ks2 * 16 + fg * 8 + e;
        float v = (kr < K_REAL && t < T_DIM) ? linv * Dl[kr][t] : 0.0f;
        _Float16 h = (_Float16)v;
        _Float16 l = (_Float16)(v - (float)h);
        int base = (p * 2) * 512 + lane * 8 + e;
        wsD[base]       = h;
        wsD[base + 512] = l;
    }
}

__global__ void __launch_bounds__(NTHREADS, 3)
fista_mfma(const float* __restrict__ Y, const float* __restrict__ ws,
           float* __restrict__ out) {
    // ping-pong y in f16 hi/lo, [buf][part][col][k-half]  (51.2 KB -> 2 blocks/CU)
    __shared__ __align__(16) _Float16 ybuf[2][2][CB][YKH];

    const float lam = ((const float*)ws)[1];
    const half8* Afp = (const half8*)((const char*)ws + WS_AFRAG_OFF);
    const half8* Dfp = (const half8*)((const char*)ws + WS_DFRAG_OFF);

    const int tid  = threadIdx.x;
    const int lane = tid & 63;
    const int mg   = __builtin_amdgcn_readfirstlane(tid >> 6); // 0..5 = M-tile
    const int col  = lane & 31;
    const int kg   = lane >> 5;       // k-group within fragment

    const int blk = blockIdx.x;
    const int b   = blk / (F_DIM / CB);
    const int f0  = (blk % (F_DIM / CB)) * CB;

    // ---- stage Y (f16 hi/lo, [part][c][t], t padded to 48) into ybuf[1] ----
    _Float16* Yst = &ybuf[1][0][0][0];    // 2*32*104*2 = 13.3 KB of 25.6 KB
    const float* Yb = Y + (size_t)b * T_DIM * F_DIM + f0;
    for (int idx = tid; idx < 48 * CB; idx += NTHREADS) {
        int t = idx >> 5, c = idx & 31;
        float v = (t < T_DIM) ? Yb[(size_t)t * F_DIM + c] : 0.0f;
        _Float16 h = (_Float16)v;
        _Float16 l = (_Float16)(v - (float)h);
        Yst[c * YSTH + t]             = h;
        Yst[CB * YSTH + c * YSTH + t] = l;
    }
    // ---- zero ybuf[0] (y=0 initial iterate, incl. all pad rows) ----
    int4* zb = (int4*)&ybuf[0][0][0][0];
    for (int idx = tid; idx < (2 * CB * YKH * 2) / 16; idx += NTHREADS)
        zb[idx] = int4{0, 0, 0, 0};
    __syncthreads();

    // ---- DtY via 32x32x16 MFMA (3-term split), C-layout regs ----
    f32x16 dty;
    #pragma unroll
    for (int r = 0; r < 16; ++r) dty[r] = 0.0f;
    #pragma unroll
    for (int ks2 = 0; ks2 < KT; ++ks2) {
        const _Float16* yp = Yst + col * YSTH + ks2 * 16 + kg * 8;
        half8 yh = *(const half8*)yp;
        half8 yl = *(const half8*)(yp + CB * YSTH);
        half8 dh = Dfp[((mg * KT + ks2) * 2 + 0) * 64 + lane];
        half8 dl = Dfp[((mg * KT + ks2) * 2 + 1) * 64 + lane];
        dty = MFMA32(dh, yh, dty);
        dty = MFMA32(dh, yl, dty);
        dty = MFMA32(dl, yh, dty);
    }
    __syncthreads();   // staging reads done before iter-0 writes ybuf[1]

    // ---- persistent A-hat fragments: 11 ks x 2 terms x 4 regs = 88 regs
    //      STATIC indexing only (dynamic -> scratch spill, R6 lesson) ----
    half8 Af[KS16][2];
    #pragma unroll
    for (int ks = 0; ks < KS16; ++ks)
        #pragma unroll
        for (int term = 0; term < 2; ++term)
            Af[ks][term] = Afp[((mg * KS16 + ks) * 2 + term) * 64 + lane];

    float xold[16];
    #pragma unroll
    for (int r = 0; r < 16; ++r) xold[r] = 0.0f;

    float tm = 1.0f;
    int p = 0;
    for (int it = 0; it < MAXIT; ++it) {
        f32x16 acc = dty;

        // K sweep: 11 steps x 3 MFMA (Ah*yh + Ah*yl + Al*yh); k=160 folded in
        #pragma unroll
        for (int ks = 0; ks < KS16; ++ks) {
            const _Float16* yp = &ybuf[p][0][col][ks * 16 + kg * 8];
            half8 yh = *(const half8*)yp;
            half8 yl = *(const half8*)(yp + CB * YKH);
            acc = MFMA32(Af[ks][0], yh, acc);
            acc = MFMA32(Af[ks][0], yl, acc);
            acc = MFMA32(Af[ks][1], yh, acc);
        }

        float tn = 0.5f * (1.0f + sqrtf(1.0f + 4.0f * tm * tm));
        float tt = (tm - 1.0f) / tn;
        tm = tn;

        // epilogue: C-layout row = (r&3) + 8*(r>>2) + 4*kg (+ mg*32)
        #pragma unroll
        for (int c4 = 0; c4 < 4; ++c4) {
            if (mg < 5 || c4 < 2) {   // wave 5: only rows 160-175 (zeros beyond 160)
                half4 hv, lv;
                #pragma unroll
                for (int j = 0; j < 4; ++j) {
                    int r = c4 * 4 + j;
                    float v  = acc[r];
                    float s  = fmaxf(fabsf(v) - lam, 0.0f);
                    float xn = copysignf(s, v);
                    float yn = (1.0f + tt) * xn - tt * xold[r];
                    xold[r] = xn;
                    _Float16 h = (_Float16)yn;
                    hv[j] = h;
                    lv[j] = (_Float16)(yn - (float)h);
                }
                int kh = mg * 32 + c4 * 8 + kg * 4;   // half index within col
                *(half4*)&ybuf[1 - p][0][col][kh] = hv;
                *(half4*)&ybuf[1 - p][1][col][kh] = lv;
            }
        }
        __syncthreads();
        p ^= 1;
    }

    // ---- output x (fp32) ----
    float* ob = out + (size_t)b * K_REAL * F_DIM + f0 + col;
    #pragma unroll
    for (int r = 0; r < 16; ++r) {
        int k = mg * 32 + (r >> 2) * 8 + kg * 4 + (r & 3);
        if (k < K_REAL) ob[(size_t)k * F_DIM] = xold[r];
    }
}

extern "C" void kernel_launch(void* const* d_in, const int* in_sizes, int n_in,
                              void* d_out, int out_size, void* d_ws, size_t ws_size,
                              hipStream_t stream) {
    const float* x      = (const float*)d_in[0];
    const float* Drr    = (const float*)d_in[1];
    const float* Dtheta = (const float*)d_in[2];
    float* out = (float*)d_out;
    float* ws  = (float*)d_ws;

    hipLaunchKernelGGL(setup_kernel, dim3(1), dim3(SETUP_T), 0, stream,
                       Drr, Dtheta, ws);
    hipLaunchKernelGGL(fista_mfma, dim3((B_DIM * F_DIM) / CB), dim3(NTHREADS),
                       0, stream, x, ws, out);
}

// Round 13
// 696.475 us; speedup vs baseline: 1.2017x; 1.2017x over previous
//
#include <hip/hip_runtime.h>
#include <math.h>

typedef _Float16 half8 __attribute__((ext_vector_type(8)));
typedef _Float16 half4 __attribute__((ext_vector_type(4)));
typedef float    f32x4 __attribute__((ext_vector_type(4)));

#define T_DIM 36
#define N_AT 40
#define K_REAL 161
#define MT 11           // 11 M-tiles of 16 = 176 rows (161 real; pad tile dropped)
#define KSM 5           // 5 MFMA K-steps of 32 = 160; k=160 handled in epilogue
#define KS2 2           // DtY K-steps over t (36 -> 64)
#define B_DIM 2
#define F_DIM 20480
#define CB 32           // columns per block (2 N-tiles per wave)
#define NTHREADS 256    // 4 waves; 2 blocks/CU (register-limited 2 waves/SIMD)
#define SETUP_T 512     // MUST be 512: frag builder needs tid>>3 to span 64 lanes
#define MAXIT 100
#define YK 200          // padded k-stride in y LDS (f16; 100 dwords)
#define YST 72          // Ystage t-stride (f16 units)

// ws layout (bytes):
//  [0..64): scalars  (float linv @0, float lam @4)
//  A-hat frags: idx = (Mt*KSM+ks)*2+term, 64 lanes x 8 f16 (1 KB each)
//  Dthat frags: idx = (Mt*KS2+ks2)*2+term
//  A160: 176 f32 (exact fp32 column 160 of A-hat)
#define WS_AFRAG_OFF 64
#define AFRAG_BYTES (MT * KSM * 2 * 1024)
#define WS_DFRAG_OFF (WS_AFRAG_OFF + AFRAG_BYTES)
#define DFRAG_BYTES (MT * KS2 * 2 * 1024)
#define WS_A160_OFF (WS_DFRAG_OFF + DFRAG_BYTES)

#define MFMA16(a, b, c) __builtin_amdgcn_mfma_f32_16x16x32_f16((a), (b), (c), 0, 0, 0)

__global__ void setup_kernel(const float* __restrict__ Drr,
                             const float* __restrict__ Dtheta,
                             float* __restrict__ ws) {
    __shared__ float Dl[K_REAL][T_DIM];   // normalized dictionary, [col k][t]
    __shared__ float red[SETUP_T];
    __shared__ float s_linv;
    int tid = threadIdx.x;

    // ---- build normalized dictionary columns ----
    if (tid < K_REAL) {
        float col[T_DIM];
        if (tid == 0) {
            for (int i = 0; i < T_DIM; ++i) col[i] = 1.0f;
        } else {
            int q = (tid - 1) / N_AT, n = (tid - 1) % N_AT;
            float r = Drr[n], th = Dtheta[n];
            float ri = 1.0f;
            for (int i = 0; i < T_DIM; ++i) {
                float c = cosf((float)i * th), s = sinf((float)i * th);
                float sign = (i & 1) ? -1.0f : 1.0f;
                float v;
                if (q == 0)      v = ri * c;
                else if (q == 1) v = sign * ri * c;
                else if (q == 2) v = ri * s;
                else             v = sign * ri * s;
                col[i] = v;
                ri *= r;
            }
        }
        float ss = 0.0f;
        for (int i = 0; i < T_DIM; ++i) ss += col[i] * col[i];
        float G = sqrtf(ss);
        float Ginv = (G == 0.0f) ? (1.0f / sqrtf((float)T_DIM)) : (1.0f / G);
        for (int i = 0; i < T_DIM; ++i) Dl[tid][i] = col[i] * Ginv;
    }
    __syncthreads();

    // ---- linv = 1 / frobenius(DtD) ----
    float local = 0.0f;
    for (int p = tid; p < K_REAL * K_REAL; p += SETUP_T) {
        int a = p / K_REAL, b = p % K_REAL;
        float dot = 0.0f;
        for (int i = 0; i < T_DIM; ++i) dot += Dl[a][i] * Dl[b][i];
        local += dot * dot;
    }
    red[tid] = local;
    __syncthreads();
    if (tid == 0) {
        float tot = 0.0f;
        for (int i = 0; i < SETUP_T; ++i) tot += red[i];
        float linv = 1.0f / sqrtf(tot);
        s_linv = linv;
        ws[0] = linv;
        ws[1] = 0.1f * linv;
    }
    __syncthreads();
    float linv = s_linv;

    // ---- A-hat fragments: A = I - linv * DtD, f16 hi/lo, A-operand layout ----
    // lane = tid>>3 (0..63 @512thr), e = tid&7 ; m = Mt*16+(lane&15) ; k = ks*32+(lane>>4)*8+e
    _Float16* wsA = (_Float16*)((char*)ws + WS_AFRAG_OFF);
    int lane = tid >> 3, e = tid & 7;
    int fm = lane & 15, fq = lane >> 4;
    for (int p = 0; p < MT * KSM; ++p) {
        int Mt = p / KSM, ks = p % KSM;
        int m = Mt * 16 + fm;
        int k = ks * 32 + fq * 8 + e;      // k <= 159: always real
        float v = 0.0f;
        if (m < K_REAL) {
            float dot = 0.0f;
            for (int t = 0; t < T_DIM; ++t) dot += Dl[m][t] * Dl[k][t];
            v = ((m == k) ? 1.0f : 0.0f) - linv * dot;
        }
        _Float16 h = (_Float16)v;
        _Float16 l = (_Float16)(v - (float)h);
        int base = (p * 2) * 512 + lane * 8 + e;
        wsA[base]       = h;
        wsA[base + 512] = l;
    }

    // ---- Dthat fragments: Dthat[k][t] = linv * D[t][k], A-operand layout over t ----
    _Float16* wsD = (_Float16*)((char*)ws + WS_DFRAG_OFF);
    for (int p = 0; p < MT * KS2; ++p) {
        int Mt = p / KS2, ks2 = p % KS2;
        int kr = Mt * 16 + fm;
        int t  = ks2 * 16 * 2 + fq * 8 + e;
        float v = (kr < K_REAL && t < T_DIM) ? linv * Dl[kr][t] : 0.0f;
        _Float16 h = (_Float16)v;
        _Float16 l = (_Float16)(v - (float)h);
        int base = (p * 2) * 512 + lane * 8 + e;
        wsD[base]       = h;
        wsD[base + 512] = l;
    }

    // ---- A160: exact fp32 column 160 of A-hat (rank-1 k=160 term; A symmetric) ----
    float* wsC = (float*)((char*)ws + WS_A160_OFF);
    if (tid < MT * 16) {
        int m = tid;
        float v = 0.0f;
        if (m < K_REAL) {
            float dot = 0.0f;
            for (int t = 0; t < T_DIM; ++t) dot += Dl[m][t] * Dl[160][t];
            v = ((m == 160) ? 1.0f : 0.0f) - linv * dot;
        }
        wsC[m] = v;
    }
}

__global__ void __launch_bounds__(NTHREADS, 2)
fista_mfma(const float* __restrict__ Y, const float* __restrict__ ws,
           float* __restrict__ out) {
    // ping-pong y in f16 hi/lo, [buf][part][col][k]  (51.2 KB; regs limit to 2 blk/CU)
    __shared__ __align__(16) _Float16 ybuf[2][2][CB][YK];

    const float lam = ((const float*)ws)[1];
    const half8* Afp = (const half8*)((const char*)ws + WS_AFRAG_OFF); // 64 half8/frag
    const half8* Dfp = (const half8*)((const char*)ws + WS_DFRAG_OFF);
    const float* A160 = (const float*)((const char*)ws + WS_A160_OFF);

    const int tid  = threadIdx.x;
    const int lane = tid & 63;
    const int mg   = __builtin_amdgcn_readfirstlane(tid >> 6); // 0..3 (M-group)
    const int mlc  = (mg == 3) ? 2 : 3;   // wave 3 owns tiles 9,10 only
    const int quad = lane >> 4;
    const int cl   = lane & 15;           // column within an N-tile

    const int blk = blockIdx.x;
    const int b   = blk / (F_DIM / CB);
    const int f0  = (blk % (F_DIM / CB)) * CB;

    // ---- stage Y (f16 hi/lo, [part][c][t]) into ybuf[1] area ----
    _Float16* Yst = &ybuf[1][0][0][0];
    const float* Yb = Y + (size_t)b * T_DIM * F_DIM + f0;
    for (int idx = tid; idx < 64 * CB; idx += NTHREADS) {
        int t = idx / CB, c = idx % CB;
        float v = (t < T_DIM) ? Yb[(size_t)t * F_DIM + c] : 0.0f;
        _Float16 h = (_Float16)v;
        _Float16 l = (_Float16)(v - (float)h);
        Yst[c * YST + t]            = h;
        Yst[CB * YST + c * YST + t] = l;
    }
    // ---- zero ybuf[0] (y = 0 initial iterate, incl. pad rows) ----
    int4* zb = (int4*)&ybuf[0][0][0][0];
    for (int idx = tid; idx < (2 * CB * YK * 2) / 16; idx += NTHREADS)
        zb[idx] = int4{0, 0, 0, 0};
    __syncthreads();

    // ---- DtY via MFMA (3-term split), per N-tile, lands in C-layout regs ----
    f32x4 dty[3][2];
    #pragma unroll
    for (int ml = 0; ml < 3; ++ml)
        #pragma unroll
        for (int ng = 0; ng < 2; ++ng) dty[ml][ng] = f32x4{0.f, 0.f, 0.f, 0.f};
    #pragma unroll
    for (int ks2 = 0; ks2 < KS2; ++ks2) {
        #pragma unroll
        for (int ng = 0; ng < 2; ++ng) {
            const _Float16* yp = Yst + (ng * 16 + cl) * YST + ks2 * 32 + quad * 8;
            half8 yh = *(const half8*)yp;
            half8 yl = *(const half8*)(yp + CB * YST);
            #pragma unroll
            for (int ml = 0; ml < 3; ++ml) {
                if (ml < mlc) {
                    int Mt = mg * 3 + ml;
                    half8 dh = Dfp[((Mt * KS2 + ks2) * 2 + 0) * 64 + lane];
                    half8 dl = Dfp[((Mt * KS2 + ks2) * 2 + 1) * 64 + lane];
                    dty[ml][ng] = MFMA16(dh, yh, dty[ml][ng]);
                    dty[ml][ng] = MFMA16(dh, yl, dty[ml][ng]);
                    dty[ml][ng] = MFMA16(dl, yh, dty[ml][ng]);
                }
            }
        }
    }
    __syncthreads();   // all waves done reading Yst before iter-0 writes ybuf[1]

    // ---- persistent A-hat fragments (120 regs) + fp32 col 160
    //      STATIC indexing only (dynamic -> scratch spill, R6 lesson) ----
    half8 Af[3][KSM][2];
    float a160[3][4];
    #pragma unroll
    for (int ml = 0; ml < 3; ++ml) {
        if (ml < mlc) {
            #pragma unroll
            for (int ks = 0; ks < KSM; ++ks)
                #pragma unroll
                for (int term = 0; term < 2; ++term)
                    Af[ml][ks][term] =
                        Afp[(((mg * 3 + ml) * KSM + ks) * 2 + term) * 64 + lane];
            #pragma unroll
            for (int r = 0; r < 4; ++r)
                a160[ml][r] = A160[(mg * 3 + ml) * 16 + quad * 4 + r];
        }
    }

    // ---- per-block random phase jitter: de-phase-lock co-resident blocks so
    //      one block's MFMA sweep overlaps the other's VALU epilogue ----
    {
        unsigned ph = (blockIdx.x * 2654435761u) >> 25;   // 7 bits: 0..127
        for (unsigned i = 0; i < ph; ++i) __builtin_amdgcn_s_sleep(1);  // ~64 cyc each
    }

    float xold[3][2][4];
    #pragma unroll
    for (int ml = 0; ml < 3; ++ml)
        #pragma unroll
        for (int ng = 0; ng < 2; ++ng)
            #pragma unroll
            for (int r = 0; r < 4; ++r) xold[ml][ng][r] = 0.0f;

    float tm = 1.0f;
    int p = 0;
    for (int it = 0; it < MAXIT; ++it) {
        f32x4 acc[3][2];

        // K-sweep; first step seeds acc with dty as the MFMA C operand (no copies)
        #pragma unroll
        for (int ks = 0; ks < KSM; ++ks) {
            #pragma unroll
            for (int ng = 0; ng < 2; ++ng) {
                const _Float16* yp = &ybuf[p][0][ng * 16 + cl][ks * 32 + quad * 8];
                half8 yh = *(const half8*)yp;
                half8 yl = *(const half8*)(yp + CB * YK);
                #pragma unroll
                for (int ml = 0; ml < 3; ++ml) {
                    if (ml < mlc) {
                        f32x4 c0 = (ks == 0) ? dty[ml][ng] : acc[ml][ng];
                        c0 = MFMA16(Af[ml][ks][0], yh, c0);
                        c0 = MFMA16(Af[ml][ks][0], yl, c0);
                        acc[ml][ng] = MFMA16(Af[ml][ks][1], yh, c0);
                    }
                }
            }
        }

        float tn = 0.5f * (1.0f + sqrtf(1.0f + 4.0f * tm * tm));
        float tt = (tm - 1.0f) / tn;
        tm = tn;

        // epilogue: rank-1 k=160 term folded in (exact fp32)
        #pragma unroll
        for (int ng = 0; ng < 2; ++ng) {
            float y160 = (float)ybuf[p][0][ng * 16 + cl][160]
                       + (float)ybuf[p][1][ng * 16 + cl][160];
            #pragma unroll
            for (int ml = 0; ml < 3; ++ml) {
                if (ml < mlc) {
                    half4 hv, lv;
                    #pragma unroll
                    for (int r = 0; r < 4; ++r) {
                        float v  = acc[ml][ng][r] + a160[ml][r] * y160;  // = A*y + DtY
                        float s  = fmaxf(fabsf(v) - lam, 0.0f);
                        float xn = copysignf(s, v);
                        float yn = (1.0f + tt) * xn - tt * xold[ml][ng][r];
                        xold[ml][ng][r] = xn;
                        _Float16 h = (_Float16)yn;
                        hv[r] = h;
                        lv[r] = (_Float16)(yn - (float)h);
                    }
                    int k0 = (mg * 3 + ml) * 16 + quad * 4;
                    *(half4*)&ybuf[1 - p][0][ng * 16 + cl][k0] = hv;
                    *(half4*)&ybuf[1 - p][1][ng * 16 + cl][k0] = lv;
                }
            }
        }
        __syncthreads();
        p ^= 1;
    }

    // ---- output x (fp32) ----
    #pragma unroll
    for (int ng = 0; ng < 2; ++ng) {
        float* ob = out + (size_t)b * K_REAL * F_DIM + f0 + ng * 16 + cl;
        #pragma unroll
        for (int ml = 0; ml < 3; ++ml)
            if (ml < mlc)
                #pragma unroll
                for (int r = 0; r < 4; ++r) {
                    int k = (mg * 3 + ml) * 16 + quad * 4 + r;
                    if (k < K_REAL) ob[(size_t)k * F_DIM] = xold[ml][ng][r];
                }
    }
}

extern "C" void kernel_launch(void* const* d_in, const int* in_sizes, int n_in,
                              void* d_out, int out_size, void* d_ws, size_t ws_size,
                              hipStream_t stream) {
    const float* x      = (const float*)d_in[0];
    const float* Drr    = (const float*)d_in[1];
    const float* Dtheta = (const float*)d_in[2];
    float* out = (float*)d_out;
    float* ws  = (float*)d_ws;

    hipLaunchKernelGGL(setup_kernel, dim3(1), dim3(SETUP_T), 0, stream,
                       Drr, Dtheta, ws);
    hipLaunchKernelGGL(fista_mfma, dim3((B_DIM * F_DIM) / CB), dim3(NTHREADS),
                       0, stream, x, ws, out);
}

// Round 14
// 678.486 us; speedup vs baseline: 1.2336x; 1.0265x over previous
//
#include <hip/hip_runtime.h>
#include <math.h>

typedef _Float16 half8 __attribute__((ext_vector_type(8)));
typedef _Float16 half4 __attribute__((ext_vector_type(4)));
typedef float    f32x4 __attribute__((ext_vector_type(4)));

#define T_DIM 36
#define N_AT 40
#define K_REAL 161
#define MT 11           // 11 M-tiles of 16 = 176 rows (161 real; pad tile dropped)
#define KSM 5           // 5 MFMA K-steps of 32 = 160; k=160 is a rank-1 term in sweep
#define KS2 2           // DtY K-steps over t (36 -> 64)
#define B_DIM 2
#define F_DIM 20480
#define CB 32           // columns per block = 2 independent 16-col groups
#define NTHREADS 256    // 4 waves; 2 blocks/CU (register-limited 2 waves/SIMD)
#define SETUP_T 512     // MUST be 512: frag builder needs tid>>3 to span 64 lanes
#define MAXIT 100
#define YK 200          // padded k-stride in y LDS (f16)
#define YST 72          // staging t-stride (f16)

// ws layout (bytes): scalars | A-hat frags | Dthat frags | A160 fp32
#define WS_AFRAG_OFF 64
#define AFRAG_BYTES (MT * KSM * 2 * 1024)
#define WS_DFRAG_OFF (WS_AFRAG_OFF + AFRAG_BYTES)
#define DFRAG_BYTES (MT * KS2 * 2 * 1024)
#define WS_A160_OFF (WS_DFRAG_OFF + DFRAG_BYTES)

#define MFMA16(a, b, c) __builtin_amdgcn_mfma_f32_16x16x32_f16((a), (b), (c), 0, 0, 0)

__global__ void setup_kernel(const float* __restrict__ Drr,
                             const float* __restrict__ Dtheta,
                             float* __restrict__ ws) {
    __shared__ float Dl[K_REAL][T_DIM];
    __shared__ float red[SETUP_T];
    __shared__ float s_linv;
    int tid = threadIdx.x;

    if (tid < K_REAL) {
        float col[T_DIM];
        if (tid == 0) {
            for (int i = 0; i < T_DIM; ++i) col[i] = 1.0f;
        } else {
            int q = (tid - 1) / N_AT, n = (tid - 1) % N_AT;
            float r = Drr[n], th = Dtheta[n];
            float ri = 1.0f;
            for (int i = 0; i < T_DIM; ++i) {
                float c = cosf((float)i * th), s = sinf((float)i * th);
                float sign = (i & 1) ? -1.0f : 1.0f;
                float v;
                if (q == 0)      v = ri * c;
                else if (q == 1) v = sign * ri * c;
                else if (q == 2) v = ri * s;
                else             v = sign * ri * s;
                col[i] = v;
                ri *= r;
            }
        }
        float ss = 0.0f;
        for (int i = 0; i < T_DIM; ++i) ss += col[i] * col[i];
        float G = sqrtf(ss);
        float Ginv = (G == 0.0f) ? (1.0f / sqrtf((float)T_DIM)) : (1.0f / G);
        for (int i = 0; i < T_DIM; ++i) Dl[tid][i] = col[i] * Ginv;
    }
    __syncthreads();

    float local = 0.0f;
    for (int p = tid; p < K_REAL * K_REAL; p += SETUP_T) {
        int a = p / K_REAL, b = p % K_REAL;
        float dot = 0.0f;
        for (int i = 0; i < T_DIM; ++i) dot += Dl[a][i] * Dl[b][i];
        local += dot * dot;
    }
    red[tid] = local;
    __syncthreads();
    if (tid == 0) {
        float tot = 0.0f;
        for (int i = 0; i < SETUP_T; ++i) tot += red[i];
        float linv = 1.0f / sqrtf(tot);
        s_linv = linv;
        ws[0] = linv;
        ws[1] = 0.1f * linv;
    }
    __syncthreads();
    float linv = s_linv;

    _Float16* wsA = (_Float16*)((char*)ws + WS_AFRAG_OFF);
    int lane = tid >> 3, e = tid & 7;
    int fm = lane & 15, fq = lane >> 4;
    for (int p = 0; p < MT * KSM; ++p) {
        int Mt = p / KSM, ks = p % KSM;
        int m = Mt * 16 + fm;
        int k = ks * 32 + fq * 8 + e;
        float v = 0.0f;
        if (m < K_REAL) {
            float dot = 0.0f;
            for (int t = 0; t < T_DIM; ++t) dot += Dl[m][t] * Dl[k][t];
            v = ((m == k) ? 1.0f : 0.0f) - linv * dot;
        }
        _Float16 h = (_Float16)v;
        _Float16 l = (_Float16)(v - (float)h);
        int base = (p * 2) * 512 + lane * 8 + e;
        wsA[base]       = h;
        wsA[base + 512] = l;
    }

    _Float16* wsD = (_Float16*)((char*)ws + WS_DFRAG_OFF);
    for (int p = 0; p < MT * KS2; ++p) {
        int Mt = p / KS2, ks2 = p % KS2;
        int kr = Mt * 16 + fm;
        int t  = ks2 * 32 + fq * 8 + e;
        float v = (kr < K_REAL && t < T_DIM) ? linv * Dl[kr][t] : 0.0f;
        _Float16 h = (_Float16)v;
        _Float16 l = (_Float16)(v - (float)h);
        int base = (p * 2) * 512 + lane * 8 + e;
        wsD[base]       = h;
        wsD[base + 512] = l;
    }

    float* wsC = (float*)((char*)ws + WS_A160_OFF);
    if (tid < MT * 16) {
        int m = tid;
        float v = 0.0f;
        if (m < K_REAL) {
            float dot = 0.0f;
            for (int t = 0; t < T_DIM; ++t) dot += Dl[m][t] * Dl[160][t];
            v = ((m == 160) ? 1.0f : 0.0f) - linv * dot;
        }
        wsC[m] = v;
    }
}

// ---- device helpers: compile-time group G keeps all register indexing static ----
template <int G>
__device__ __forceinline__ void sweep_g(f32x4 (&acc)[3], const f32x4 (&dty)[3],
                                        const half8 (&Af)[3][KSM][2],
                                        const float (&a160)[3][4],
                                        const _Float16 (*Yh)[YK],
                                        const _Float16 (*Yl)[YK],
                                        int cl, int quad, int mlc) {
    #pragma unroll
    for (int ks = 0; ks < KSM; ++ks) {
        half8 yh = *(const half8*)&Yh[G * 16 + cl][ks * 32 + quad * 8];
        half8 yl = *(const half8*)&Yl[G * 16 + cl][ks * 32 + quad * 8];
        #pragma unroll
        for (int ml = 0; ml < 3; ++ml) {
            if (ml < mlc) {
                f32x4 c0 = (ks == 0) ? dty[ml] : acc[ml];
                c0 = MFMA16(Af[ml][ks][0], yh, c0);
                c0 = MFMA16(Af[ml][ks][0], yl, c0);
                acc[ml] = MFMA16(Af[ml][ks][1], yh, c0);
            }
        }
    }
    // rank-1 k=160 term (exact fp32), same y-epoch as the MFMA reads
    float y160 = (float)Yh[G * 16 + cl][160] + (float)Yl[G * 16 + cl][160];
    #pragma unroll
    for (int ml = 0; ml < 3; ++ml)
        if (ml < mlc)
            #pragma unroll
            for (int r = 0; r < 4; ++r)
                acc[ml][r] += a160[ml][r] * y160;
}

template <int G>
__device__ __forceinline__ void epi_g(const f32x4 (&acc)[3], float (&xold)[3][4],
                                      _Float16 (*Yh)[YK], _Float16 (*Yl)[YK],
                                      float lam, float tt,
                                      int cl, int quad, int mg, int mlc) {
    #pragma unroll
    for (int ml = 0; ml < 3; ++ml) {
        if (ml < mlc) {
            half4 hv, lv;
            #pragma unroll
            for (int r = 0; r < 4; ++r) {
                float v  = acc[ml][r];
                float s  = fmaxf(fabsf(v) - lam, 0.0f);
                float xn = copysignf(s, v);
                float yn = (1.0f + tt) * xn - tt * xold[ml][r];
                xold[ml][r] = xn;
                _Float16 h = (_Float16)yn;
                hv[r] = h;
                lv[r] = (_Float16)(yn - (float)h);
            }
            int k0 = (mg * 3 + ml) * 16 + quad * 4;
            *(half4*)&Yh[G * 16 + cl][k0] = hv;
            *(half4*)&Yl[G * 16 + cl][k0] = lv;
        }
    }
}

__global__ void __launch_bounds__(NTHREADS, 2)
fista_mfma(const float* __restrict__ Y, const float* __restrict__ ws,
           float* __restrict__ out) {
    // single y buffer (software-pipelined groups make ping-pong unnecessary)
    __shared__ __align__(16) _Float16 Yh[CB][YK];   // 12.8 KB
    __shared__ __align__(16) _Float16 Yl[CB][YK];   // 12.8 KB

    const float lam = ((const float*)ws)[1];
    const half8* Afp = (const half8*)((const char*)ws + WS_AFRAG_OFF);
    const half8* Dfp = (const half8*)((const char*)ws + WS_DFRAG_OFF);
    const float* A160 = (const float*)((const char*)ws + WS_A160_OFF);

    const int tid  = threadIdx.x;
    const int lane = tid & 63;
    const int mg   = __builtin_amdgcn_readfirstlane(tid >> 6); // 0..3
    const int mlc  = (mg == 3) ? 2 : 3;
    const int quad = lane >> 4;
    const int cl   = lane & 15;

    const int blk = blockIdx.x;
    const int b   = blk / (F_DIM / CB);
    const int f0  = (blk % (F_DIM / CB)) * CB;

    // ---- stage Y (f16 hi/lo, [c][t]) into the Yh/Yl space temporarily ----
    _Float16* sh = &Yh[0][0];
    _Float16* sl = &Yl[0][0];
    const float* Yb = Y + (size_t)b * T_DIM * F_DIM + f0;
    for (int idx = tid; idx < 64 * CB; idx += NTHREADS) {
        int t = idx / CB, c = idx % CB;
        float v = (t < T_DIM) ? Yb[(size_t)t * F_DIM + c] : 0.0f;
        _Float16 h = (_Float16)v;
        _Float16 l = (_Float16)(v - (float)h);
        sh[c * YST + t] = h;
        sl[c * YST + t] = l;
    }
    __syncthreads();

    // ---- DtY via MFMA (3-term split), group-major dty[2][3] ----
    f32x4 dty[2][3];
    #pragma unroll
    for (int g = 0; g < 2; ++g)
        #pragma unroll
        for (int ml = 0; ml < 3; ++ml) dty[g][ml] = f32x4{0.f, 0.f, 0.f, 0.f};
    #pragma unroll
    for (int ks2 = 0; ks2 < KS2; ++ks2) {
        #pragma unroll
        for (int g = 0; g < 2; ++g) {
            half8 yh = *(const half8*)&sh[(g * 16 + cl) * YST + ks2 * 32 + quad * 8];
            half8 yl = *(const half8*)&sl[(g * 16 + cl) * YST + ks2 * 32 + quad * 8];
            #pragma unroll
            for (int ml = 0; ml < 3; ++ml) {
                if (ml < mlc) {
                    int Mt = mg * 3 + ml;
                    half8 dh = Dfp[((Mt * KS2 + ks2) * 2 + 0) * 64 + lane];
                    half8 dl = Dfp[((Mt * KS2 + ks2) * 2 + 1) * 64 + lane];
                    dty[g][ml] = MFMA16(dh, yh, dty[g][ml]);
                    dty[g][ml] = MFMA16(dh, yl, dty[g][ml]);
                    dty[g][ml] = MFMA16(dl, yh, dty[g][ml]);
                }
            }
        }
    }
    __syncthreads();

    // ---- zero the y buffer (y_0 = 0, incl. pad rows) ----
    {
        int4* z1 = (int4*)&Yh[0][0];
        int4* z2 = (int4*)&Yl[0][0];
        for (int idx = tid; idx < (CB * YK * 2) / 16; idx += NTHREADS) {
            z1[idx] = int4{0, 0, 0, 0};
            z2[idx] = int4{0, 0, 0, 0};
        }
    }

    // ---- persistent A-hat fragments + fp32 col 160 (STATIC indexing only) ----
    half8 Af[3][KSM][2];
    float a160[3][4];
    #pragma unroll
    for (int ml = 0; ml < 3; ++ml) {
        if (ml < mlc) {
            #pragma unroll
            for (int ks = 0; ks < KSM; ++ks)
                #pragma unroll
                for (int term = 0; term < 2; ++term)
                    Af[ml][ks][term] =
                        Afp[(((mg * 3 + ml) * KSM + ks) * 2 + term) * 64 + lane];
            #pragma unroll
            for (int r = 0; r < 4; ++r)
                a160[ml][r] = A160[(mg * 3 + ml) * 16 + quad * 4 + r];
        }
    }
    __syncthreads();

    float xoldA[3][4], xoldB[3][4];
    #pragma unroll
    for (int ml = 0; ml < 3; ++ml)
        #pragma unroll
        for (int r = 0; r < 4; ++r) { xoldA[ml][r] = 0.0f; xoldB[ml][r] = 0.0f; }

    // acc for step 1 is free: y_0 = 0 -> acc_1 = dty
    f32x4 accA[3], accB[3];
    #pragma unroll
    for (int ml = 0; ml < 3; ++ml) { accA[ml] = dty[0][ml]; accB[ml] = dty[1][ml]; }

    // t-sequence: t_0=1 -> t_1=(1+sqrt5)/2, tt_1 = 0
    float tm = 1.61803398875f;
    float tt_prev = 0.0f;

    // P1: epi(g0, s=1)
    epi_g<0>(accA, xoldA, Yh, Yl, lam, tt_prev, cl, quad, mg, mlc);
    __syncthreads();

    for (int s = 2; s <= MAXIT; ++s) {
        float tn = 0.5f * (1.0f + sqrtf(1.0f + 4.0f * tm * tm));
        float tt_cur = (tm - 1.0f) / tn;
        tm = tn;

        // phase: sweep(g0, s)  ||  epi(g1, s-1)   [independent -> co-scheduled]
        sweep_g<0>(accA, dty[0], Af, a160, Yh, Yl, cl, quad, mlc);
        epi_g<1>(accB, xoldB, Yh, Yl, lam, tt_prev, cl, quad, mg, mlc);
        __syncthreads();

        // phase: sweep(g1, s)  ||  epi(g0, s)
        sweep_g<1>(accB, dty[1], Af, a160, Yh, Yl, cl, quad, mlc);
        epi_g<0>(accA, xoldA, Yh, Yl, lam, tt_cur, cl, quad, mg, mlc);
        __syncthreads();

        tt_prev = tt_cur;
    }
    // drain: epi(g1, s=MAXIT)
    epi_g<1>(accB, xoldB, Yh, Yl, lam, tt_prev, cl, quad, mg, mlc);

    // ---- output x (fp32) ----
    #pragma unroll
    for (int g = 0; g < 2; ++g) {
        float* ob = out + (size_t)b * K_REAL * F_DIM + f0 + g * 16 + cl;
        #pragma unroll
        for (int ml = 0; ml < 3; ++ml)
            if (ml < mlc)
                #pragma unroll
                for (int r = 0; r < 4; ++r) {
                    int k = (mg * 3 + ml) * 16 + quad * 4 + r;
                    float xv = g ? xoldB[ml][r] : xoldA[ml][r];
                    if (k < K_REAL) ob[(size_t)k * F_DIM] = xv;
                }
    }
}

extern "C" void kernel_launch(void* const* d_in, const int* in_sizes, int n_in,
                              void* d_out, int out_size, void* d_ws, size_t ws_size,
                              hipStream_t stream) {
    const float* x      = (const float*)d_in[0];
    const float* Drr    = (const float*)d_in[1];
    const float* Dtheta = (const float*)d_in[2];
    float* out = (float*)d_out;
    float* ws  = (float*)d_ws;

    hipLaunchKernelGGL(setup_kernel, dim3(1), dim3(SETUP_T), 0, stream,
                       Drr, Dtheta, ws);
    hipLaunchKernelGGL(fista_mfma, dim3((B_DIM * F_DIM) / CB), dim3(NTHREADS),
                       0, stream, x, ws, out);
}

// Round 16
// 673.081 us; speedup vs baseline: 1.2435x; 1.0080x over previous
//
#include <hip/hip_runtime.h>
#include <math.h>

typedef _Float16 half8 __attribute__((ext_vector_type(8)));
typedef _Float16 half4 __attribute__((ext_vector_type(4)));
typedef __fp16   fp16x2 __attribute__((ext_vector_type(2)));   // cvt_pkrtz return type
typedef float    f32x4 __attribute__((ext_vector_type(4)));

#define T_DIM 36
#define N_AT 40
#define K_REAL 161
#define MT 11           // 11 M-tiles of 16 = 176 rows (161 real; pad tile dropped)
#define KSM 5           // 5 MFMA K-steps of 32 = 160; k=160 is a rank-1 term in sweep
#define KS2 2           // DtY K-steps over t (36 -> 64)
#define B_DIM 2
#define F_DIM 20480
#define CB 32           // columns per block = 2 independent 16-col groups
#define NTHREADS 256    // 4 waves; 2 blocks/CU (register-limited 2 waves/SIMD)
#define SETUP_T 512     // MUST be 512: frag builder needs tid>>3 to span 64 lanes
#define MAXIT 100
#define YK 200          // padded k-stride in y LDS (f16)
#define YST 72          // staging t-stride (f16)

// ws layout (bytes): scalars | A-hat frags | Dthat frags | A160 fp32
#define WS_AFRAG_OFF 64
#define AFRAG_BYTES (MT * KSM * 2 * 1024)
#define WS_DFRAG_OFF (WS_AFRAG_OFF + AFRAG_BYTES)
#define DFRAG_BYTES (MT * KS2 * 2 * 1024)
#define WS_A160_OFF (WS_DFRAG_OFF + DFRAG_BYTES)

#define MFMA16(a, b, c) __builtin_amdgcn_mfma_f32_16x16x32_f16((a), (b), (c), 0, 0, 0)

__global__ void setup_kernel(const float* __restrict__ Drr,
                             const float* __restrict__ Dtheta,
                             float* __restrict__ ws) {
    __shared__ float Dl[K_REAL][T_DIM];
    __shared__ float red[SETUP_T];
    __shared__ float s_linv;
    int tid = threadIdx.x;

    if (tid < K_REAL) {
        float col[T_DIM];
        if (tid == 0) {
            for (int i = 0; i < T_DIM; ++i) col[i] = 1.0f;
        } else {
            int q = (tid - 1) / N_AT, n = (tid - 1) % N_AT;
            float r = Drr[n], th = Dtheta[n];
            float ri = 1.0f;
            for (int i = 0; i < T_DIM; ++i) {
                float c = cosf((float)i * th), s = sinf((float)i * th);
                float sign = (i & 1) ? -1.0f : 1.0f;
                float v;
                if (q == 0)      v = ri * c;
                else if (q == 1) v = sign * ri * c;
                else if (q == 2) v = ri * s;
                else             v = sign * ri * s;
                col[i] = v;
                ri *= r;
            }
        }
        float ss = 0.0f;
        for (int i = 0; i < T_DIM; ++i) ss += col[i] * col[i];
        float G = sqrtf(ss);
        float Ginv = (G == 0.0f) ? (1.0f / sqrtf((float)T_DIM)) : (1.0f / G);
        for (int i = 0; i < T_DIM; ++i) Dl[tid][i] = col[i] * Ginv;
    }
    __syncthreads();

    float local = 0.0f;
    for (int p = tid; p < K_REAL * K_REAL; p += SETUP_T) {
        int a = p / K_REAL, b = p % K_REAL;
        float dot = 0.0f;
        for (int i = 0; i < T_DIM; ++i) dot += Dl[a][i] * Dl[b][i];
        local += dot * dot;
    }
    red[tid] = local;
    __syncthreads();
    if (tid == 0) {
        float tot = 0.0f;
        for (int i = 0; i < SETUP_T; ++i) tot += red[i];
        float linv = 1.0f / sqrtf(tot);
        s_linv = linv;
        ws[0] = linv;
        ws[1] = 0.1f * linv;
    }
    __syncthreads();
    float linv = s_linv;

    _Float16* wsA = (_Float16*)((char*)ws + WS_AFRAG_OFF);
    int lane = tid >> 3, e = tid & 7;
    int fm = lane & 15, fq = lane >> 4;
    for (int p = 0; p < MT * KSM; ++p) {
        int Mt = p / KSM, ks = p % KSM;
        int m = Mt * 16 + fm;
        int k = ks * 32 + fq * 8 + e;
        float v = 0.0f;
        if (m < K_REAL) {
            float dot = 0.0f;
            for (int t = 0; t < T_DIM; ++t) dot += Dl[m][t] * Dl[k][t];
            v = ((m == k) ? 1.0f : 0.0f) - linv * dot;
        }
        _Float16 h = (_Float16)v;
        _Float16 l = (_Float16)(v - (float)h);
        int base = (p * 2) * 512 + lane * 8 + e;
        wsA[base]       = h;
        wsA[base + 512] = l;
    }

    _Float16* wsD = (_Float16*)((char*)ws + WS_DFRAG_OFF);
    for (int p = 0; p < MT * KS2; ++p) {
        int Mt = p / KS2, ks2 = p % KS2;
        int kr = Mt * 16 + fm;
        int t  = ks2 * 32 + fq * 8 + e;
        float v = (kr < K_REAL && t < T_DIM) ? linv * Dl[kr][t] : 0.0f;
        _Float16 h = (_Float16)v;
        _Float16 l = (_Float16)(v - (float)h);
        int base = (p * 2) * 512 + lane * 8 + e;
        wsD[base]       = h;
        wsD[base + 512] = l;
    }

    float* wsC = (float*)((char*)ws + WS_A160_OFF);
    if (tid < MT * 16) {
        int m = tid;
        float v = 0.0f;
        if (m < K_REAL) {
            float dot = 0.0f;
            for (int t = 0; t < T_DIM; ++t) dot += Dl[m][t] * Dl[160][t];
            v = ((m == 160) ? 1.0f : 0.0f) - linv * dot;
        }
        wsC[m] = v;
    }
}

// ---- device helpers: compile-time group G keeps all register indexing static ----
template <int G>
__device__ __forceinline__ void sweep_g(f32x4 (&acc)[3], const f32x4 (&dty)[3],
                                        const half8 (&Af)[3][KSM][2],
                                        const float (&a160)[3][4],
                                        const _Float16 (*Yh)[YK],
                                        const _Float16 (*Yl)[YK],
                                        int cl, int quad, int mlc) {
    #pragma unroll
    for (int ks = 0; ks < KSM; ++ks) {
        half8 yh = *(const half8*)&Yh[G * 16 + cl][ks * 32 + quad * 8];
        half8 yl = *(const half8*)&Yl[G * 16 + cl][ks * 32 + quad * 8];
        #pragma unroll
        for (int ml = 0; ml < 3; ++ml) {
            if (ml < mlc) {
                f32x4 c0 = (ks == 0) ? dty[ml] : acc[ml];
                c0 = MFMA16(Af[ml][ks][0], yh, c0);
                c0 = MFMA16(Af[ml][ks][0], yl, c0);
                acc[ml] = MFMA16(Af[ml][ks][1], yh, c0);
            }
        }
    }
    // rank-1 k=160 term (exact fp32), same y-epoch as the MFMA reads
    float y160 = (float)Yh[G * 16 + cl][160] + (float)Yl[G * 16 + cl][160];
    #pragma unroll
    for (int ml = 0; ml < 3; ++ml)
        if (ml < mlc)
            #pragma unroll
            for (int r = 0; r < 4; ++r)
                acc[ml][r] += a160[ml][r] * y160;
}

template <int G>
__device__ __forceinline__ void epi_g(const f32x4 (&acc)[3], float (&xold)[3][4],
                                      _Float16 (*Yh)[YK], _Float16 (*Yl)[YK],
                                      float lam, float tt,
                                      int cl, int quad, int mg, int mlc) {
    #pragma unroll
    for (int ml = 0; ml < 3; ++ml) {
        if (ml < mlc) {
            float yn[4];
            #pragma unroll
            for (int r = 0; r < 4; ++r) {
                float v  = acc[ml][r];
                float s  = fmaxf(fabsf(v) - lam, 0.0f);
                float xn = copysignf(s, v);
                yn[r] = xn + tt * (xn - xold[ml][r]);   // == (1+tt)xn - tt*xold
                xold[ml][r] = xn;
            }
            // packed f32->f16 (RTZ); hi/lo split stays exact: lo = yn - (f32)hi
            fp16x2 h01 = __builtin_amdgcn_cvt_pkrtz(yn[0], yn[1]);
            fp16x2 h23 = __builtin_amdgcn_cvt_pkrtz(yn[2], yn[3]);
            float l0 = yn[0] - (float)h01[0];
            float l1 = yn[1] - (float)h01[1];
            float l2 = yn[2] - (float)h23[0];
            float l3 = yn[3] - (float)h23[1];
            fp16x2 l01 = __builtin_amdgcn_cvt_pkrtz(l0, l1);
            fp16x2 l23 = __builtin_amdgcn_cvt_pkrtz(l2, l3);
            half4 hv, lv;
            hv[0] = (_Float16)h01[0]; hv[1] = (_Float16)h01[1];
            hv[2] = (_Float16)h23[0]; hv[3] = (_Float16)h23[1];
            lv[0] = (_Float16)l01[0]; lv[1] = (_Float16)l01[1];
            lv[2] = (_Float16)l23[0]; lv[3] = (_Float16)l23[1];
            int k0 = (mg * 3 + ml) * 16 + quad * 4;
            *(half4*)&Yh[G * 16 + cl][k0] = hv;
            *(half4*)&Yl[G * 16 + cl][k0] = lv;
        }
    }
}

__global__ void __launch_bounds__(NTHREADS, 2)
fista_mfma(const float* __restrict__ Y, const float* __restrict__ ws,
           float* __restrict__ out) {
    // single y buffer (software-pipelined groups make ping-pong unnecessary)
    __shared__ __align__(16) _Float16 Yh[CB][YK];   // 12.8 KB
    __shared__ __align__(16) _Float16 Yl[CB][YK];   // 12.8 KB

    const float lam = ((const float*)ws)[1];
    const half8* Afp = (const half8*)((const char*)ws + WS_AFRAG_OFF);
    const half8* Dfp = (const half8*)((const char*)ws + WS_DFRAG_OFF);
    const float* A160 = (const float*)((const char*)ws + WS_A160_OFF);

    const int tid  = threadIdx.x;
    const int lane = tid & 63;
    const int mg   = __builtin_amdgcn_readfirstlane(tid >> 6); // 0..3
    const int mlc  = (mg == 3) ? 2 : 3;
    const int quad = lane >> 4;
    const int cl   = lane & 15;

    const int blk = blockIdx.x;
    const int b   = blk / (F_DIM / CB);
    const int f0  = (blk % (F_DIM / CB)) * CB;

    // ---- stage Y (f16 hi/lo, [c][t]) into the Yh/Yl space temporarily ----
    _Float16* sh = &Yh[0][0];
    _Float16* sl = &Yl[0][0];
    const float* Yb = Y + (size_t)b * T_DIM * F_DIM + f0;
    for (int idx = tid; idx < 64 * CB; idx += NTHREADS) {
        int t = idx / CB, c = idx % CB;
        float v = (t < T_DIM) ? Yb[(size_t)t * F_DIM + c] : 0.0f;
        _Float16 h = (_Float16)v;
        _Float16 l = (_Float16)(v - (float)h);
        sh[c * YST + t] = h;
        sl[c * YST + t] = l;
    }
    __syncthreads();

    // ---- DtY via MFMA (3-term split), group-major dty[2][3] ----
    f32x4 dty[2][3];
    #pragma unroll
    for (int g = 0; g < 2; ++g)
        #pragma unroll
        for (int ml = 0; ml < 3; ++ml) dty[g][ml] = f32x4{0.f, 0.f, 0.f, 0.f};
    #pragma unroll
    for (int ks2 = 0; ks2 < KS2; ++ks2) {
        #pragma unroll
        for (int g = 0; g < 2; ++g) {
            half8 yh = *(const half8*)&sh[(g * 16 + cl) * YST + ks2 * 32 + quad * 8];
            half8 yl = *(const half8*)&sl[(g * 16 + cl) * YST + ks2 * 32 + quad * 8];
            #pragma unroll
            for (int ml = 0; ml < 3; ++ml) {
                if (ml < mlc) {
                    int Mt = mg * 3 + ml;
                    half8 dh = Dfp[((Mt * KS2 + ks2) * 2 + 0) * 64 + lane];
                    half8 dl = Dfp[((Mt * KS2 + ks2) * 2 + 1) * 64 + lane];
                    dty[g][ml] = MFMA16(dh, yh, dty[g][ml]);
                    dty[g][ml] = MFMA16(dh, yl, dty[g][ml]);
                    dty[g][ml] = MFMA16(dl, yh, dty[g][ml]);
                }
            }
        }
    }
    __syncthreads();

    // ---- zero the y buffer (y_0 = 0, incl. pad rows) ----
    {
        int4* z1 = (int4*)&Yh[0][0];
        int4* z2 = (int4*)&Yl[0][0];
        for (int idx = tid; idx < (CB * YK * 2) / 16; idx += NTHREADS) {
            z1[idx] = int4{0, 0, 0, 0};
            z2[idx] = int4{0, 0, 0, 0};
        }
    }

    // ---- persistent A-hat fragments + fp32 col 160 (STATIC indexing only) ----
    half8 Af[3][KSM][2];
    float a160[3][4];
    #pragma unroll
    for (int ml = 0; ml < 3; ++ml) {
        if (ml < mlc) {
            #pragma unroll
            for (int ks = 0; ks < KSM; ++ks)
                #pragma unroll
                for (int term = 0; term < 2; ++term)
                    Af[ml][ks][term] =
                        Afp[(((mg * 3 + ml) * KSM + ks) * 2 + term) * 64 + lane];
            #pragma unroll
            for (int r = 0; r < 4; ++r)
                a160[ml][r] = A160[(mg * 3 + ml) * 16 + quad * 4 + r];
        }
    }
    __syncthreads();

    float xoldA[3][4], xoldB[3][4];
    #pragma unroll
    for (int ml = 0; ml < 3; ++ml)
        #pragma unroll
        for (int r = 0; r < 4; ++r) { xoldA[ml][r] = 0.0f; xoldB[ml][r] = 0.0f; }

    // acc for step 1 is free: y_0 = 0 -> acc_1 = dty
    f32x4 accA[3], accB[3];
    #pragma unroll
    for (int ml = 0; ml < 3; ++ml) { accA[ml] = dty[0][ml]; accB[ml] = dty[1][ml]; }

    // t-sequence: t_0=1 -> t_1=(1+sqrt5)/2, tt_1 = 0
    float tm = 1.61803398875f;
    float tt_prev = 0.0f;

    // P1: epi(g0, s=1)
    epi_g<0>(accA, xoldA, Yh, Yl, lam, tt_prev, cl, quad, mg, mlc);
    __syncthreads();

    for (int s = 2; s <= MAXIT; ++s) {
        float tn = 0.5f * (1.0f + sqrtf(1.0f + 4.0f * tm * tm));
        float tt_cur = (tm - 1.0f) / tn;
        tm = tn;

        // phase: sweep(g0, s)  ||  epi(g1, s-1)   [independent -> co-scheduled]
        sweep_g<0>(accA, dty[0], Af, a160, Yh, Yl, cl, quad, mlc);
        epi_g<1>(accB, xoldB, Yh, Yl, lam, tt_prev, cl, quad, mg, mlc);
        __syncthreads();

        // phase: sweep(g1, s)  ||  epi(g0, s)
        sweep_g<1>(accB, dty[1], Af, a160, Yh, Yl, cl, quad, mlc);
        epi_g<0>(accA, xoldA, Yh, Yl, lam, tt_cur, cl, quad, mg, mlc);
        __syncthreads();

        tt_prev = tt_cur;
    }
    // drain: epi(g1, s=MAXIT)
    epi_g<1>(accB, xoldB, Yh, Yl, lam, tt_prev, cl, quad, mg, mlc);

    // ---- output x (fp32) ----
    #pragma unroll
    for (int g = 0; g < 2; ++g) {
        float* ob = out + (size_t)b * K_REAL * F_DIM + f0 + g * 16 + cl;
        #pragma unroll
        for (int ml = 0; ml < 3; ++ml)
            if (ml < mlc)
                #pragma unroll
                for (int r = 0; r < 4; ++r) {
                    int k = (mg * 3 + ml) * 16 + quad * 4 + r;
                    float xv = g ? xoldB[ml][r] : xoldA[ml][r];
                    if (k < K_REAL) ob[(size_t)k * F_DIM] = xv;
                }
    }
}

extern "C" void kernel_launch(void* const* d_in, const int* in_sizes, int n_in,
                              void* d_out, int out_size, void* d_ws, size_t ws_size,
                              hipStream_t stream) {
    const float* x      = (const float*)d_in[0];
    const float* Drr    = (const float*)d_in[1];
    const float* Dtheta = (const float*)d_in[2];
    float* out = (float*)d_out;
    float* ws  = (float*)d_ws;

    hipLaunchKernelGGL(setup_kernel, dim3(1), dim3(SETUP_T), 0, stream,
                       Drr, Dtheta, ws);
    hipLaunchKernelGGL(fista_mfma, dim3((B_DIM * F_DIM) / CB), dim3(NTHREADS),
                       0, stream, x, ws, out);
}